// Round 9
// baseline (800.387 us; speedup 1.0000x reference)
//
#include <hip/hip_runtime.h>
#include <stdint.h>

#define B_  16
#define QL  2048
#define KL  2048
#define FD  128
#define BQ  64
#define BK  32
#define NSTEP (KL/BK)
#define PSTR  40
#define WS_HALF (B_*KL*FD)   // shorts per converted array (8 MB)

typedef __attribute__((ext_vector_type(8))) short bf16x8;
typedef __attribute__((ext_vector_type(4))) float f32x4;

__device__ __forceinline__ unsigned short f2b(float f) {
  union { float f; unsigned u; } x; x.f = f;
  return (unsigned short)((x.u + 0x8000u) >> 16);
}

// ---- pre-pass 1: K fp32 -> bf16, same layout ----
__global__ __launch_bounds__(256) void conv_k(const float* __restrict__ kp,
                                              unsigned short* __restrict__ kb) {
  int idx = (blockIdx.x * 256 + threadIdx.x) * 4;
  float4 u = *(const float4*)(kp + idx);
  ushort4 s4; s4.x = f2b(u.x); s4.y = f2b(u.y); s4.z = f2b(u.z); s4.w = f2b(u.w);
  *(ushort4*)(kb + idx) = s4;
}

// ---- pre-pass 2: V fp32 [b][k][f] -> bf16 tiled-transposed [b][kt][f][32] ----
__global__ __launch_bounds__(256) void conv_vt(const float* __restrict__ vp,
                                               unsigned short* __restrict__ vt) {
  __shared__ float tl[32 * 132];
  const int t = threadIdx.x, b = blockIdx.x >> 6, kt = blockIdx.x & 63;
  const int r = t >> 3, f0 = (t & 7) * 16;
  const float* src = vp + ((long long)(b * KL + kt * 32 + r)) * FD + f0;
  #pragma unroll
  for (int i = 0; i < 4; ++i)
    *(float4*)&tl[r * 132 + f0 + 4 * i] = *(const float4*)(src + 4 * i);
  __syncthreads();
  const int f = t >> 1, half = t & 1;
  bf16x8 o0, o1;
  #pragma unroll
  for (int j = 0; j < 8; ++j)  o0[j] = (short)f2b(tl[(half * 16 + j) * 132 + f]);
  #pragma unroll
  for (int j = 0; j < 8; ++j)  o1[j] = (short)f2b(tl[(half * 16 + 8 + j) * 132 + f]);
  unsigned short* dst = vt + ((long long)((b * 64 + kt) * FD + f)) * 32 + half * 16;
  *(bf16x8*)dst = o0;
  *(bf16x8*)(dst + 8) = o1;
}

// out = (sum_k !attn*e^s*V)/l - sum_k !attn*!alibi*d*bscale*V,  l = sum_k e^s
// BARRIER-FREE K-loop: waves fully independent. K/V frags read direct from
// L2-resident bf16 workspace; masks direct coalesced dword streams with
// distance-1 register prefetch; only wave-private P/T LDS round-trip remains.
__global__ __launch_bounds__(256, 2) void alibi_attn(
    const unsigned short* __restrict__ kbp,   // bf16 K [b][k][f]
    const unsigned short* __restrict__ vtp,   // bf16 V^T tiles [b][kt][f][32]
    const float* __restrict__ qp,
    const float* __restrict__ cqp,
    const float* __restrict__ ckp,
    const int* __restrict__ amp,
    const int* __restrict__ almp,
    const float* __restrict__ bsp,
    const float* __restrict__ rmp,
    float* __restrict__ outp)
{
  __shared__ unsigned short plds[4][2][16 * PSTR];   // 10 KB wave-private P/T

  const int t    = threadIdx.x;
  const int w    = t >> 6;
  const int lane = t & 63;
  const int l15  = lane & 15;
  const int q4   = lane >> 4;

  const int bid  = blockIdx.x;
  const int xcd  = bid & 7, slot = bid >> 3;
  const int b    = (xcd << 1) | (slot >> 5);
  const int qbase = (slot & 31) * BQ;

  const float bscale = bsp[0] / rmp[0];
  const float sl2 = 0.08838834764831845f * 1.44269504089f;  // scale*log2(e)

  // ---- prologue: Q frags + coords_q direct from global ----
  bf16x8 qfrag[4];
  {
    const float* qrow = qp + ((long long)(b * QL + qbase + w * 16 + l15)) * FD;
    #pragma unroll
    for (int fs = 0; fs < 4; ++fs) {
      float4 u0 = *(const float4*)(qrow + fs * 32 + q4 * 8);
      float4 u1 = *(const float4*)(qrow + fs * 32 + q4 * 8 + 4);
      qfrag[fs][0] = (short)f2b(u0.x); qfrag[fs][1] = (short)f2b(u0.y);
      qfrag[fs][2] = (short)f2b(u0.z); qfrag[fs][3] = (short)f2b(u0.w);
      qfrag[fs][4] = (short)f2b(u1.x); qfrag[fs][5] = (short)f2b(u1.y);
      qfrag[fs][6] = (short)f2b(u1.z); qfrag[fs][7] = (short)f2b(u1.w);
    }
  }
  float cqx[4], cqy[4];
  long long mrow_base[4];
  #pragma unroll
  for (int r = 0; r < 4; ++r) {
    const int qg_ = qbase + w * 16 + q4 * 4 + r;
    float2 c2 = *(const float2*)(cqp + ((long long)(b * QL + qg_)) * 2);
    cqx[r] = c2.x; cqy[r] = c2.y;
    mrow_base[r] = ((long long)(b * QL + qg_)) * KL;
  }

  const unsigned short* kgb = kbp + (long long)b * KL * FD;
  const unsigned short* vgb = vtp + (long long)b * KL * FD;

  // ---- prefetch step 0 masks + coords_k into registers ----
  int   amv[2][8], alv[2][8];
  float ckxv[2][2], ckyv[2][2];
  #pragma unroll
  for (int s = 0; s < 2; ++s) {
    const int kg = s * 16 + l15;
    #pragma unroll
    for (int r = 0; r < 4; ++r) {
      amv[0][s * 4 + r] = __builtin_nontemporal_load(amp + mrow_base[r] + kg);
      alv[0][s * 4 + r] = __builtin_nontemporal_load(almp + mrow_base[r] + kg);
    }
    float2 c2 = *(const float2*)(ckp + ((long long)(b * KL + kg)) * 2);
    ckxv[0][s] = c2.x; ckyv[0][s] = c2.y;
  }

  f32x4 O1[8], O2[8];
  #pragma unroll
  for (int n = 0; n < 8; ++n) {
    O1[n] = (f32x4){0.f, 0.f, 0.f, 0.f};
    O2[n] = (f32x4){0.f, 0.f, 0.f, 0.f};
  }
  float lsum[4] = {0.f, 0.f, 0.f, 0.f};

  #pragma unroll 2
  for (int kt = 0; kt < NSTEP; ++kt) {
    const int cur = kt & 1, nxt = cur ^ 1;
    const int k0  = kt * BK;
    const int ktp = (kt + 1 < NSTEP) ? (kt + 1) : kt;
    const int k0p = ktp * BK;

    // ---- prefetch next step's masks + coords_k (HBM latency cover) ----
    #pragma unroll
    for (int s = 0; s < 2; ++s) {
      const int kg = k0p + s * 16 + l15;
      #pragma unroll
      for (int r = 0; r < 4; ++r) {
        amv[nxt][s * 4 + r] = __builtin_nontemporal_load(amp + mrow_base[r] + kg);
        alv[nxt][s * 4 + r] = __builtin_nontemporal_load(almp + mrow_base[r] + kg);
      }
      float2 c2 = *(const float2*)(ckp + ((long long)(b * KL + kg)) * 2);
      ckxv[nxt][s] = c2.x; ckyv[nxt][s] = c2.y;
    }

    // ---- QK^T: K frags direct from L2 workspace ----
    const unsigned short* kt_ptr = kgb + (long long)k0 * FD;
    f32x4 S0 = (f32x4){0.f, 0.f, 0.f, 0.f};
    f32x4 S1 = (f32x4){0.f, 0.f, 0.f, 0.f};
    #pragma unroll
    for (int fs = 0; fs < 4; ++fs) {
      bf16x8 kb0 = *(const bf16x8*)(kt_ptr + (l15)      * FD + fs * 32 + q4 * 8);
      bf16x8 kb1 = *(const bf16x8*)(kt_ptr + (16 + l15) * FD + fs * 32 + q4 * 8);
      S0 = __builtin_amdgcn_mfma_f32_16x16x32_bf16(qfrag[fs], kb0, S0, 0, 0, 0);
      S1 = __builtin_amdgcn_mfma_f32_16x16x32_bf16(qfrag[fs], kb1, S1, 0, 0, 0);
    }

    // ---- transform with register-prefetched masks ----
    #pragma unroll
    for (int s = 0; s < 2; ++s) {
      const f32x4 Sv = s ? S1 : S0;
      #pragma unroll
      for (int r = 0; r < 4; ++r) {
        int am = amv[cur][s * 4 + r], al = alv[cur][s * 4 + r];
        float e = __builtin_amdgcn_exp2f(Sv[r] * sl2);
        lsum[r] += e;
        float dx = cqx[r] - ckxv[cur][s], dy = cqy[r] - ckyv[cur][s];
        float d  = sqrtf(fmaf(dx, dx, dy * dy)) * bscale;
        float wv = am ? 0.f : e;
        float tv = (am | al) ? 0.f : d;
        const int mm = q4 * 4 + r, c = s * 16 + l15;
        plds[w][0][mm * PSTR + c] = f2b(wv);
        plds[w][1][mm * PSTR + c] = f2b(tv);
      }
    }

    // ---- PV: P/T from wave-private LDS, V^T frags direct from L2 ----
    bf16x8 aw = *(const bf16x8*)&plds[w][0][l15 * PSTR + q4 * 8];
    bf16x8 at = *(const bf16x8*)&plds[w][1][l15 * PSTR + q4 * 8];
    const unsigned short* vt_ptr = vgb + (long long)kt * (BK * FD);
    #pragma unroll
    for (int n = 0; n < 8; ++n) {
      bf16x8 vb = *(const bf16x8*)(vt_ptr + (n * 16 + l15) * 32 + q4 * 8);
      O1[n] = __builtin_amdgcn_mfma_f32_16x16x32_bf16(aw, vb, O1[n], 0, 0, 0);
      O2[n] = __builtin_amdgcn_mfma_f32_16x16x32_bf16(at, vb, O2[n], 0, 0, 0);
    }
  }

  // ---- epilogue: reduce lsum over the quad's 16 lanes, combine, store ----
  #pragma unroll
  for (int off = 1; off < 16; off <<= 1) {
    #pragma unroll
    for (int r = 0; r < 4; ++r) lsum[r] += __shfl_xor(lsum[r], off, 64);
  }
  float linv[4];
  #pragma unroll
  for (int r = 0; r < 4; ++r) linv[r] = 1.0f / lsum[r];

  #pragma unroll
  for (int n = 0; n < 8; ++n) {
    #pragma unroll
    for (int r = 0; r < 4; ++r) {
      const int qg_ = qbase + w * 16 + q4 * 4 + r;
      const int f   = n * 16 + l15;
      float val = O1[n][r] * linv[r] - O2[n][r];
      __builtin_nontemporal_store(val, outp + ((long long)(b * QL + qg_)) * FD + f);
    }
  }
}

extern "C" void kernel_launch(void* const* d_in, const int* in_sizes, int n_in,
                              void* d_out, int out_size, void* d_ws, size_t ws_size,
                              hipStream_t stream) {
  const float* q   = (const float*)d_in[0];
  const float* k   = (const float*)d_in[1];
  const float* v   = (const float*)d_in[2];
  const float* cq  = (const float*)d_in[3];
  const float* ck  = (const float*)d_in[4];
  const int*   am  = (const int*)d_in[5];
  const int*   alm = (const int*)d_in[6];
  const float* bs  = (const float*)d_in[7];
  const float* rm  = (const float*)d_in[8];
  float*       out = (float*)d_out;

  unsigned short* kb = (unsigned short*)d_ws;            // 8 MB bf16 K
  unsigned short* vt = kb + WS_HALF;                     // 8 MB bf16 V^T tiles

  hipLaunchKernelGGL(conv_k,  dim3(WS_HALF / 1024), dim3(256), 0, stream, k, kb);
  hipLaunchKernelGGL(conv_vt, dim3(B_ * 64),        dim3(256), 0, stream, v, vt);

  dim3 grid(B_ * (QL / BQ));   // 512 blocks, 2/CU
  dim3 block(256);
  hipLaunchKernelGGL(alibi_attn, grid, block, 0, stream,
                     kb, vt, q, cq, ck, am, alm, bs, rm, out);
}

// Round 10
// 660.769 us; speedup vs baseline: 1.2113x; 1.2113x over previous
//
#include <hip/hip_runtime.h>
#include <stdint.h>

#define B_  16
#define QL  2048
#define KL  2048
#define FD  128
#define BQ  64
#define BK  32
#define NSTEP (KL/BK)

#define KSTR  136        // K-tile LDS row stride (shorts)
#define VTOFF 4352       // 32*136
#define VTSTR 36         // V^T LDS row stride (shorts); b128 reads conflict-free
#define BUFS  8960       // 4352 + 128*36 shorts per buffer
#define PSTR  40
#define WS_HALF (B_*KL*FD)   // shorts per converted array (8 MB)

typedef __attribute__((ext_vector_type(8))) short bf16x8;
typedef __attribute__((ext_vector_type(4))) float f32x4;

__device__ __forceinline__ unsigned short f2b(float f) {
  union { float f; unsigned u; } x; x.f = f;
  return (unsigned short)((x.u + 0x8000u) >> 16);
}

// ---- pre-pass 1: K fp32 -> bf16, same layout ----
__global__ __launch_bounds__(256) void conv_k(const float* __restrict__ kp,
                                              unsigned short* __restrict__ kb) {
  int idx = (blockIdx.x * 256 + threadIdx.x) * 4;
  float4 u = *(const float4*)(kp + idx);
  ushort4 s4; s4.x = f2b(u.x); s4.y = f2b(u.y); s4.z = f2b(u.z); s4.w = f2b(u.w);
  *(ushort4*)(kb + idx) = s4;
}

// ---- pre-pass 2: V fp32 [b][k][f] -> bf16 tiled-transposed [b][kt][f][32] ----
__global__ __launch_bounds__(256) void conv_vt(const float* __restrict__ vp,
                                               unsigned short* __restrict__ vt) {
  __shared__ float tl[32 * 132];
  const int t = threadIdx.x, b = blockIdx.x >> 6, kt = blockIdx.x & 63;
  const int r = t >> 3, f0 = (t & 7) * 16;
  const float* src = vp + ((long long)(b * KL + kt * 32 + r)) * FD + f0;
  #pragma unroll
  for (int i = 0; i < 4; ++i)
    *(float4*)&tl[r * 132 + f0 + 4 * i] = *(const float4*)(src + 4 * i);
  __syncthreads();
  const int f = t >> 1, half = t & 1;
  bf16x8 o0, o1;
  #pragma unroll
  for (int j = 0; j < 8; ++j)  o0[j] = (short)f2b(tl[(half * 16 + j) * 132 + f]);
  #pragma unroll
  for (int j = 0; j < 8; ++j)  o1[j] = (short)f2b(tl[(half * 16 + 8 + j) * 132 + f]);
  unsigned short* dst = vt + ((long long)((b * 64 + kt) * FD + f)) * 32 + half * 16;
  *(bf16x8*)dst = o0;
  *(bf16x8*)(dst + 8) = o1;
}

// out = (sum_k !attn*e^s*V)/l - sum_k !attn*!alibi*d*bscale*V,  l = sum_k e^s
// Cooperative LDS staging (dist-2 register pipeline) + raw s_barrier that
// drains ONLY lgkmcnt: in-flight VMEM (masks dist-1, K/V dist-2) crosses
// the barrier, defeating the vmcnt(0) convoy stall.
__global__ __launch_bounds__(256, 2) void alibi_attn(
    const unsigned short* __restrict__ kbp,   // bf16 K [b][k][f]
    const unsigned short* __restrict__ vtp,   // bf16 V^T tiles [b][kt][f][32]
    const float* __restrict__ qp,
    const float* __restrict__ cqp,
    const float* __restrict__ ckp,
    const int* __restrict__ amp,
    const int* __restrict__ almp,
    const float* __restrict__ bsp,
    const float* __restrict__ rmp,
    float* __restrict__ outp)
{
  __shared__ unsigned short kv[2 * BUFS];            // 35 KB K + V^T dbuf
  __shared__ unsigned short plds[4][2][16 * PSTR];   // 10 KB wave-private P/T

  const int t    = threadIdx.x;
  const int w    = t >> 6;
  const int lane = t & 63;
  const int l15  = lane & 15;
  const int q4   = lane >> 4;

  const int bid  = blockIdx.x;
  const int xcd  = bid & 7, slot = bid >> 3;
  const int b    = (xcd << 1) | (slot >> 5);
  const int qbase = (slot & 31) * BQ;

  const float bscale = bsp[0] / rmp[0];
  const float sl2 = 0.08838834764831845f * 1.44269504089f;  // scale*log2(e)

  const int kr_st = t >> 3, kc_st = (t & 7) * 16;  // K staging
  const int vf_st = t >> 1, vh_st = (t & 1) * 16;  // V staging

  // ---- prologue: Q tile -> LDS buf0 (transient), grab A-frags + coords ----
  {
    const float* qg = qp + ((long long)(b * QL + qbase)) * FD;
    #pragma unroll
    for (int i = 0; i < 8; ++i) {
      int idx = t + 256 * i;
      float4 u = ((const float4*)qg)[idx];
      int row = idx >> 5, col = (idx & 31) * 4;
      ushort4 s4; s4.x = f2b(u.x); s4.y = f2b(u.y); s4.z = f2b(u.z); s4.w = f2b(u.w);
      *(ushort4*)&kv[row * KSTR + col] = s4;
    }
  }
  __syncthreads();
  bf16x8 qfrag[4];
  {
    const int m = w * 16 + l15;
    #pragma unroll
    for (int fs = 0; fs < 4; ++fs)
      qfrag[fs] = *(const bf16x8*)&kv[m * KSTR + fs * 32 + q4 * 8];
  }
  float cqx[4], cqy[4];
  long long mrow_base[4];
  #pragma unroll
  for (int r = 0; r < 4; ++r) {
    const int qg_ = qbase + w * 16 + q4 * 4 + r;
    float2 c2 = *(const float2*)(cqp + ((long long)(b * QL + qg_)) * 2);
    cqx[r] = c2.x; cqy[r] = c2.y;
    mrow_base[r] = ((long long)(b * QL + qg_)) * KL;
  }
  __syncthreads();

  const unsigned short* kgb = kbp + (long long)b * KL * FD;
  const unsigned short* vgb = vtp + (long long)b * KL * FD;

  // ---- masks step 0 (regs), K/V tile 0 -> LDS buf0, K/V tile 1 -> regs set1 ----
  int   amv[2][8], alv[2][8];
  float ckxv[2][2], ckyv[2][2];
  bf16x8 kreg[2][2], vreg[2][2];
  #pragma unroll
  for (int s = 0; s < 2; ++s) {
    const int kg = s * 16 + l15;
    #pragma unroll
    for (int r = 0; r < 4; ++r) {
      amv[0][s * 4 + r] = __builtin_nontemporal_load(amp + mrow_base[r] + kg);
      alv[0][s * 4 + r] = __builtin_nontemporal_load(almp + mrow_base[r] + kg);
    }
    float2 c2 = *(const float2*)(ckp + ((long long)(b * KL + kg)) * 2);
    ckxv[0][s] = c2.x; ckyv[0][s] = c2.y;
  }
  {
    bf16x8 k0l = *(const bf16x8*)(kgb + kr_st * FD + kc_st);
    bf16x8 k1l = *(const bf16x8*)(kgb + kr_st * FD + kc_st + 8);
    bf16x8 v0l = *(const bf16x8*)(vgb + t * 16);
    bf16x8 v1l = *(const bf16x8*)(vgb + t * 16 + 8);
    *(bf16x8*)&kv[kr_st * KSTR + kc_st]     = k0l;
    *(bf16x8*)&kv[kr_st * KSTR + kc_st + 8] = k1l;
    *(bf16x8*)&kv[VTOFF + vf_st * VTSTR + vh_st]     = v0l;
    *(bf16x8*)&kv[VTOFF + vf_st * VTSTR + vh_st + 8] = v1l;
    // tile 1 into register set 1 (drained at bottom of body 0)
    kreg[1][0] = *(const bf16x8*)(kgb + (BK + kr_st) * FD + kc_st);
    kreg[1][1] = *(const bf16x8*)(kgb + (BK + kr_st) * FD + kc_st + 8);
    vreg[1][0] = *(const bf16x8*)(vgb + BK * FD + t * 16);
    vreg[1][1] = *(const bf16x8*)(vgb + BK * FD + t * 16 + 8);
  }
  __syncthreads();

  f32x4 O1[8], O2[8];
  #pragma unroll
  for (int n = 0; n < 8; ++n) {
    O1[n] = (f32x4){0.f, 0.f, 0.f, 0.f};
    O2[n] = (f32x4){0.f, 0.f, 0.f, 0.f};
  }
  float lsum[4] = {0.f, 0.f, 0.f, 0.f};

  #pragma unroll 2
  for (int kt = 0; kt < NSTEP; ++kt) {
    const int cur = kt & 1, nxt = cur ^ 1;
    const unsigned short* kb = kv + cur * BUFS;
    unsigned short*       nb = kv + nxt * BUFS;

    // ---- fill reg set `cur` with tile kt+2 (consumed 2 bodies later) ----
    const int ktf = (kt + 2 < NSTEP) ? (kt + 2) : (NSTEP - 1);
    kreg[cur][0] = *(const bf16x8*)(kgb + (ktf * BK + kr_st) * FD + kc_st);
    kreg[cur][1] = *(const bf16x8*)(kgb + (ktf * BK + kr_st) * FD + kc_st + 8);
    vreg[cur][0] = *(const bf16x8*)(vgb + ktf * (BK * FD) + t * 16);
    vreg[cur][1] = *(const bf16x8*)(vgb + ktf * (BK * FD) + t * 16 + 8);

    // ---- masks + coords for step kt+1 (dist-1, registers) ----
    const int ktm = (kt + 1 < NSTEP) ? (kt + 1) : kt;
    #pragma unroll
    for (int s = 0; s < 2; ++s) {
      const int kg = ktm * BK + s * 16 + l15;
      #pragma unroll
      for (int r = 0; r < 4; ++r) {
        amv[nxt][s * 4 + r] = __builtin_nontemporal_load(amp + mrow_base[r] + kg);
        alv[nxt][s * 4 + r] = __builtin_nontemporal_load(almp + mrow_base[r] + kg);
      }
      float2 c2 = *(const float2*)(ckp + ((long long)(b * KL + kg)) * 2);
      ckxv[nxt][s] = c2.x; ckyv[nxt][s] = c2.y;
    }

    // ---- QK^T over F=128 from LDS buf cur ----
    f32x4 S0 = (f32x4){0.f, 0.f, 0.f, 0.f};
    f32x4 S1 = (f32x4){0.f, 0.f, 0.f, 0.f};
    #pragma unroll
    for (int fs = 0; fs < 4; ++fs) {
      bf16x8 kb0 = *(const bf16x8*)&kb[(l15)      * KSTR + fs * 32 + q4 * 8];
      bf16x8 kb1 = *(const bf16x8*)&kb[(16 + l15) * KSTR + fs * 32 + q4 * 8];
      S0 = __builtin_amdgcn_mfma_f32_16x16x32_bf16(qfrag[fs], kb0, S0, 0, 0, 0);
      S1 = __builtin_amdgcn_mfma_f32_16x16x32_bf16(qfrag[fs], kb1, S1, 0, 0, 0);
    }

    // ---- transform with register masks (loaded last body) ----
    #pragma unroll
    for (int s = 0; s < 2; ++s) {
      const f32x4 Sv = s ? S1 : S0;
      #pragma unroll
      for (int r = 0; r < 4; ++r) {
        int am = amv[cur][s * 4 + r], al = alv[cur][s * 4 + r];
        float e = __builtin_amdgcn_exp2f(Sv[r] * sl2);
        lsum[r] += e;
        float dx = cqx[r] - ckxv[cur][s], dy = cqy[r] - ckyv[cur][s];
        float d  = sqrtf(fmaf(dx, dx, dy * dy)) * bscale;
        float wv = am ? 0.f : e;
        float tv = (am | al) ? 0.f : d;
        const int mm = q4 * 4 + r, c = s * 16 + l15;
        plds[w][0][mm * PSTR + c] = f2b(wv);
        plds[w][1][mm * PSTR + c] = f2b(tv);
      }
    }

    // ---- PV from LDS buf cur ----
    bf16x8 aw = *(const bf16x8*)&plds[w][0][l15 * PSTR + q4 * 8];
    bf16x8 at = *(const bf16x8*)&plds[w][1][l15 * PSTR + q4 * 8];
    #pragma unroll
    for (int n = 0; n < 8; ++n) {
      bf16x8 vb = *(const bf16x8*)&kb[VTOFF + (n * 16 + l15) * VTSTR + q4 * 8];
      O1[n] = __builtin_amdgcn_mfma_f32_16x16x32_bf16(aw, vb, O1[n], 0, 0, 0);
      O2[n] = __builtin_amdgcn_mfma_f32_16x16x32_bf16(at, vb, O2[n], 0, 0, 0);
    }

    // ---- drain reg set `nxt` (tile kt+1, loaded 2 bodies ago) into LDS nxt ----
    *(bf16x8*)&nb[kr_st * KSTR + kc_st]     = kreg[nxt][0];
    *(bf16x8*)&nb[kr_st * KSTR + kc_st + 8] = kreg[nxt][1];
    *(bf16x8*)&nb[VTOFF + vf_st * VTSTR + vh_st]     = vreg[nxt][0];
    *(bf16x8*)&nb[VTOFF + vf_st * VTSTR + vh_st + 8] = vreg[nxt][1];

    // barrier draining ONLY LDS: in-flight VMEM prefetches survive
    asm volatile("s_waitcnt lgkmcnt(0)\n\ts_barrier" ::: "memory");
  }

  // ---- epilogue: reduce lsum over quad lanes, combine, store ----
  #pragma unroll
  for (int off = 1; off < 16; off <<= 1) {
    #pragma unroll
    for (int r = 0; r < 4; ++r) lsum[r] += __shfl_xor(lsum[r], off, 64);
  }
  float linv[4];
  #pragma unroll
  for (int r = 0; r < 4; ++r) linv[r] = 1.0f / lsum[r];

  #pragma unroll
  for (int n = 0; n < 8; ++n) {
    #pragma unroll
    for (int r = 0; r < 4; ++r) {
      const int qg_ = qbase + w * 16 + q4 * 4 + r;
      const int f   = n * 16 + l15;
      float val = O1[n][r] * linv[r] - O2[n][r];
      __builtin_nontemporal_store(val, outp + ((long long)(b * QL + qg_)) * FD + f);
    }
  }
}

extern "C" void kernel_launch(void* const* d_in, const int* in_sizes, int n_in,
                              void* d_out, int out_size, void* d_ws, size_t ws_size,
                              hipStream_t stream) {
  const float* q   = (const float*)d_in[0];
  const float* k   = (const float*)d_in[1];
  const float* v   = (const float*)d_in[2];
  const float* cq  = (const float*)d_in[3];
  const float* ck  = (const float*)d_in[4];
  const int*   am  = (const int*)d_in[5];
  const int*   alm = (const int*)d_in[6];
  const float* bs  = (const float*)d_in[7];
  const float* rm  = (const float*)d_in[8];
  float*       out = (float*)d_out;

  unsigned short* kb = (unsigned short*)d_ws;            // 8 MB bf16 K
  unsigned short* vt = kb + WS_HALF;                     // 8 MB bf16 V^T tiles

  hipLaunchKernelGGL(conv_k,  dim3(WS_HALF / 1024), dim3(256), 0, stream, k, kb);
  hipLaunchKernelGGL(conv_vt, dim3(B_ * 64),        dim3(256), 0, stream, v, vt);

  dim3 grid(B_ * (QL / BQ));   // 512 blocks, 2/CU
  dim3 block(256);
  hipLaunchKernelGGL(alibi_attn, grid, block, 0, stream,
                     kb, vt, q, cq, ck, am, alm, bs, rm, out);
}